// Round 15
// baseline (290.268 us; speedup 1.0000x reference)
//
#include <hip/hip_runtime.h>
#include <hip/hip_bf16.h>

typedef unsigned short u16;
typedef unsigned int u32;
typedef __attribute__((ext_vector_type(8))) short short8;
typedef __attribute__((ext_vector_type(4))) float floatx4;

#define NB 32
#define NCI 256
#define NCO 256
#define NW 4096
#define NK 5

#define WSTEP 16384                     // per (cb,t): 256 co x 64 B rows (plain)
#define W2_BYTES (40 * WSTEP)           // 655360

#define XROWB 64                        // 32 ci' bf16
#define XROWS 132                       // rloc = (w-w0)+2, 0..131 (128w + halo)
#define XBUF (XROWS * XROWB)            // 8448 B
#define XSWZ(r) ((((r) >> 1) & 3) << 4) // conflict-free (r6-r14)

#define FENCE asm volatile("" ::: "memory")
#define LK0   asm volatile("s_waitcnt lgkmcnt(0)" ::: "memory")

// ---------------- pre-kernel: W fp32 -> bf16, [s=cb*5+k][co][32ci] 64-B rows ----------------

__global__ void wprep(const float* __restrict__ wgt, u16* __restrict__ W2) {
    int i = blockIdx.x * 256 + threadIdx.x;        // co*1280 + ci*5 + k
    if (i >= NCO * NCI * NK) return;
    int k  = i % NK;
    int ci = (i / NK) % NCI;
    int co = i / (NCI * NK);
    int cb = ci >> 5, cr = ci & 31;
    __hip_bfloat16 h = __float2bfloat16(wgt[i]);
    W2[((size_t)(cb * NK + k) * 256 + co) * 32 + cr] = *reinterpret_cast<u16*>(&h);
}

__device__ __forceinline__ u16 bf16bits(float f) {
    __hip_bfloat16 h = __float2bfloat16(f);
    return *reinterpret_cast<u16*>(&h);
}

// ---------------- fused conv: 256-thr blocks, 3 co-resident per CU ----------------
// grid 2048 = 2 co-tiles x 32 w-tiles x 32 b (co fastest); block 256 = 4 waves
// (2 co-strips x 2 w-strips), wave tile 64co x 64w, acc[4][4]=64 AGPR.
// af: global->reg, 1-tap dbuf (L1-hot; port-split from LDS). bf: swizzled LDS.
// One lgkmcnt(0)+s_barrier per cb; independent blocks cover each other's stalls.

__global__ __launch_bounds__(256, 3)
void conv_mfma(const float* __restrict__ x, const u16* __restrict__ W2,
               const float* __restrict__ bias, float* __restrict__ out) {
    __shared__ __align__(16) char xlds[2 * XBUF];   // 16896 B

    const int bid  = blockIdx.x;
    const int cot  = bid & 1;          // co tile: cot*128
    const int wt   = (bid >> 1) & 31;  // w tile: wt*128
    const int b    = bid >> 6;
    const int tid  = threadIdx.x;
    const int lane = tid & 63;
    const int wave = tid >> 6;         // 0..3
    const int wm   = wave >> 1;        // co strip (0..1)
    const int wn   = wave & 1;         // w strip (0..1)
    const int mrow = lane & 15;
    const int g    = lane >> 4;        // 0..3
    const int w0   = wt * 128;

    floatx4 acc[4][4];
#pragma unroll
    for (int mi = 0; mi < 4; ++mi)
#pragma unroll
        for (int ni = 0; ni < 4; ++ni)
            acc[mi][ni] = (floatx4){0.f, 0.f, 0.f, 0.f};

    const float* xb   = x + (size_t)b * NCI * NW;
    const char*  wimg = (const char*)W2;

    // x staging: thread -> one w (wloc), 16 ci (half cig); row rloc = 2 + wloc
    const int wloc = tid & 127;
    const int cig  = tid >> 7;         // 0..1
    const int soff0 = (2 + wloc) * XROWB + ((cig * 32) ^ XSWZ(2 + wloc));
    const int soff1 = (2 + wloc) * XROWB + ((cig * 32 + 16) ^ XSWZ(2 + wloc));
    const float* xcol = xb + w0 + wloc;          // + ci*NW

    // halo: rows {0,1,130,131} = w {w0-2,w0-1,w0+128,w0+129}; tid<128 writes u16
    const int hri  = (tid >> 5) & 3;
    const int hci  = tid & 31;
    const int hwg  = (hri < 2) ? (w0 - 2 + hri) : (w0 + 128 + (hri - 2));
    const int hwc  = (hwg < 0) ? 0 : ((hwg > NW - 1) ? (NW - 1) : hwg);
    const bool hok = (hwg >= 0) && (hwg < NW);
    const int hrloc = (hri < 2) ? hri : (130 + (hri - 2));
    const int hoff  = hrloc * XROWB + (((hci >> 3) ^ ((hrloc >> 1) & 3)) * 16) + (hci & 7) * 2;
    const bool hdo  = (tid < 128);

    const int afrow = cot * 128 + wm * 64 + mrow;   // +mi*16

#define AFLOAD(dst, s_)                                                          \
    {                                                                            \
        const char* wt_ = wimg + (size_t)(s_) * WSTEP;                           \
        _Pragma("unroll")                                                        \
        for (int mi = 0; mi < 4; ++mi)                                           \
            dst[mi] = *(const short8*)(wt_ + (afrow + mi * 16) * 64 + g * 16);   \
    }

    short8 af[2][4];
    float v[16];
    float hvv = 0.f;

    // ---------- prologue: stage x(0), load af(0) ----------
    {
        float v0[16];
#pragma unroll
        for (int j = 0; j < 16; ++j)
            v0[j] = xcol[(size_t)(cig * 16 + j) * NW];
        float hv0 = xb[(size_t)hci * NW + hwc];
        u32 p[8];
#pragma unroll
        for (int jp = 0; jp < 8; ++jp)
            p[jp] = (u32)bf16bits(v0[2 * jp]) | ((u32)bf16bits(v0[2 * jp + 1]) << 16);
        *(int4*)(xlds + soff0) = *(int4*)&p[0];
        *(int4*)(xlds + soff1) = *(int4*)&p[4];
        if (hdo)
            *(u16*)(xlds + hoff) = bf16bits(hok ? hv0 : 0.f);
        AFLOAD(af[0], 0);
        LK0;
    }
    FENCE; __builtin_amdgcn_s_barrier(); FENCE;

    // ---------- main loop: fully unrolled 8 cb x 5 taps ----------
#pragma unroll
    for (int cb = 0; cb < 8; ++cb) {
        const char* xcur = xlds + (cb & 1) * XBUF;
        char* xnxt       = xlds + ((cb + 1) & 1) * XBUF;
        // issue-early: x(cb+1) global loads (consumed at this cb's end; 5 taps cover)
        if (cb < 7) {
            const float* sx = xcol + (size_t)((cb + 1) * 32 + cig * 16) * NW;
#pragma unroll
            for (int j = 0; j < 16; ++j)
                v[j] = sx[(size_t)j * NW];
            hvv = xb[(size_t)((cb + 1) * 32 + hci) * NW + hwc];
        }
#pragma unroll
        for (int t = 0; t < NK; ++t) {
            const int s = cb * NK + t;          // compile-time
            if (s < 39)
                AFLOAD(af[(s + 1) & 1], s + 1);  // next tap's weights -> regs
            short8 bf[4];
#pragma unroll
            for (int ni = 0; ni < 4; ++ni) {
                int rx = wn * 64 + ni * 16 + mrow + t;
                bf[ni] = *(const short8*)(xcur + rx * XROWB + ((g * 16) ^ XSWZ(rx)));
            }
            __builtin_amdgcn_s_setprio(1);
#pragma unroll
            for (int mi = 0; mi < 4; ++mi)
#pragma unroll
                for (int ni = 0; ni < 4; ++ni)
                    acc[mi][ni] = __builtin_amdgcn_mfma_f32_16x16x32_bf16(
                        af[s & 1][mi], bf[ni], acc[mi][ni], 0, 0, 0);
            __builtin_amdgcn_s_setprio(0);
        }
        if (cb < 7) {
            // pack + write-late x(cb+1)
            u32 p[8];
#pragma unroll
            for (int jp = 0; jp < 8; ++jp)
                p[jp] = (u32)bf16bits(v[2 * jp]) | ((u32)bf16bits(v[2 * jp + 1]) << 16);
            *(int4*)(xnxt + soff0) = *(int4*)&p[0];
            *(int4*)(xnxt + soff1) = *(int4*)&p[4];
            if (hdo)
                *(u16*)(xnxt + hoff) = bf16bits(hok ? hvv : 0.f);
            LK0;
            FENCE; __builtin_amdgcn_s_barrier(); FENCE;
        }
    }

    // ---------- epilogue: contiguous per-row store order (mi -> r -> ni) ----------
#pragma unroll
    for (int mi = 0; mi < 4; ++mi) {
        int cobase = cot * 128 + wm * 64 + mi * 16 + g * 4;
        float bv[4];
#pragma unroll
        for (int r = 0; r < 4; ++r) bv[r] = bias[cobase + r];
#pragma unroll
        for (int r = 0; r < 4; ++r) {
            float* orow = out + ((size_t)b * NCO + cobase + r) * NW + w0 + wn * 64 + mrow;
#pragma unroll
            for (int ni = 0; ni < 4; ++ni)
                orow[ni * 16] = acc[mi][ni][r] + bv[r];
        }
    }
#undef AFLOAD
}

// ---------------- fallback (ws too small): naive fp32 ----------------

__global__ void conv_naive(const float* __restrict__ x, const float* __restrict__ wgt,
                           const float* __restrict__ bias, float* __restrict__ out) {
    int w  = blockIdx.x * 256 + threadIdx.x;
    int co = blockIdx.y;
    int b  = blockIdx.z;
    float acc = bias[co];
    for (int ci = 0; ci < NCI; ci++) {
        const float* xr = x + ((size_t)b * NCI + ci) * NW;
        const float* wr = wgt + ((size_t)co * NCI + ci) * NK;
#pragma unroll
        for (int k = 0; k < NK; k++) {
            int wi = w + k - 2;
            if (wi >= 0 && wi < NW) acc += xr[wi] * wr[k];
        }
    }
    out[((size_t)b * NCO + co) * NW + w] = acc;
}

// ---------------- launch ----------------

extern "C" void kernel_launch(void* const* d_in, const int* in_sizes, int n_in,
                              void* d_out, int out_size, void* d_ws, size_t ws_size,
                              hipStream_t stream) {
    const float* x    = (const float*)d_in[0];
    const float* wgt  = (const float*)d_in[1];
    const float* bias = (const float*)d_in[2];
    float* out        = (float*)d_out;

    if (ws_size < (size_t)W2_BYTES) {
        conv_naive<<<dim3(NW / 256, NCO, NB), 256, 0, stream>>>(x, wgt, bias, out);
        return;
    }

    u16* W2 = (u16*)d_ws;
    wprep<<<(NCO * NCI * NK + 255) / 256, 256, 0, stream>>>(wgt, W2);
    conv_mfma<<<2048, 256, 0, stream>>>(x, W2, bias, out);
}

// Round 16
// 244.486 us; speedup vs baseline: 1.1873x; 1.1873x over previous
//
#include <hip/hip_runtime.h>
#include <hip/hip_bf16.h>

typedef unsigned short u16;
typedef unsigned int u32;
typedef __attribute__((ext_vector_type(8))) short short8;
typedef __attribute__((ext_vector_type(4))) float floatx4;

#define NB 32
#define NCI 256
#define NCO 256
#define NW 4096
#define NK 5

#define WSTEP 16384                     // per (cb,t): 256 co x 64 B rows (plain)
#define W2_BYTES (40 * WSTEP)           // 655360

#define WTILE 64                        // w per block
#define XR 68                           // rows: w0-2 .. w0+65
#define WVBUF (XR * 64)                 // 4352 B per wave-buffer
#define XSWZ(r) ((((r) >> 1) & 3) << 4) // conflict-free (r6-r15)

#define LK0 asm volatile("s_waitcnt lgkmcnt(0)" ::: "memory")

// ---------------- pre-kernel: W fp32 -> bf16, [s=cb*5+k][co][32ci] 64-B rows ----------------

__global__ void wprep(const float* __restrict__ wgt, u16* __restrict__ W2) {
    int i = blockIdx.x * 256 + threadIdx.x;        // co*1280 + ci*5 + k
    if (i >= NCO * NCI * NK) return;
    int k  = i % NK;
    int ci = (i / NK) % NCI;
    int co = i / (NCI * NK);
    int cb = ci >> 5, cr = ci & 31;
    __hip_bfloat16 h = __float2bfloat16(wgt[i]);
    W2[((size_t)(cb * NK + k) * 256 + co) * 32 + cr] = *reinterpret_cast<u16*>(&h);
}

__device__ __forceinline__ u16 bf16bits(float f) {
    __hip_bfloat16 h = __float2bfloat16(f);
    return *reinterpret_cast<u16*>(&h);
}

// ---------------- fused conv: BARRIER-FREE, wave-private X staging ----------------
// grid 2048 = 64 w-tiles(64w) x 32 b; block 256 = 4 waves, wave = one 64-co strip
// x 64-w tile (acc[4][4]). Each wave double-buffers its OWN 68-row X slice in
// private LDS (4.35 KB/buf) -> no inter-wave sync of any kind; 3 blocks/CU
// (launch_bounds(256,3)) give 3 independent waves/SIMD for latency hiding.
// af: global->reg per tap (L1/L2-hot, r14-proven). X: fused fp32->bf16 pack.

__global__ __launch_bounds__(256, 3)
void conv_mfma(const float* __restrict__ x, const u16* __restrict__ W2,
               const float* __restrict__ bias, float* __restrict__ out) {
    __shared__ __align__(16) char xlds[4 * 2 * WVBUF];   // 34816 B

    const int bid  = blockIdx.x;
    const int wt   = bid & 63;
    const int b    = bid >> 6;
    const int tid  = threadIdx.x;
    const int lane = tid & 63;
    const int wave = tid >> 6;         // co strip: wave*64
    const int mrow = lane & 15;
    const int g    = lane >> 4;        // 0..3
    const int w0   = wt * WTILE;

    char* const wv = xlds + wave * (2 * WVBUF);   // this wave's private region

    floatx4 acc[4][4];
#pragma unroll
    for (int mi = 0; mi < 4; ++mi)
#pragma unroll
        for (int ni = 0; ni < 4; ++ni)
            acc[mi][ni] = (floatx4){0.f, 0.f, 0.f, 0.f};

    const float* xb   = x + (size_t)b * NCI * NW;
    const char*  wimg = (const char*)W2;

    // ---- per-lane staging chunks: 272 = 68 rows x 4 ci-slots; lane k-th chunk
    // c = lane + k*64 (k<4 all lanes; k=4 lanes<16). chunk: row=c>>2, slot=c&3.
    bool cvalid[5]; int woff[5]; size_t goff[5]; bool cok[5];
#pragma unroll
    for (int k = 0; k < 5; ++k) {
        int c = lane + k * 64;
        cvalid[k] = (k < 4) || (lane < 16);
        int row = c >> 2, slot = c & 3;
        int wg = w0 - 2 + row;
        cok[k] = (wg >= 0) && (wg < NW);
        int wc = (wg < 0) ? 0 : ((wg > NW - 1) ? (NW - 1) : wg);
        woff[k] = row * 64 + ((slot * 16) ^ XSWZ(row));
        goff[k] = (size_t)(slot * 8) * NW + wc;
    }

    const int afrow = wave * 64 + mrow;

    float v[40];

#define XLOAD(cb_)                                                              \
    {                                                                           \
        const float* xc = xb + (size_t)((cb_) * 32) * NW;                       \
        _Pragma("unroll")                                                       \
        for (int k = 0; k < 5; ++k)                                             \
            if (cvalid[k]) {                                                    \
                const float* s_ = xc + goff[k];                                 \
                _Pragma("unroll")                                               \
                for (int j = 0; j < 8; ++j)                                     \
                    v[k * 8 + j] = s_[(size_t)j * NW];                          \
            }                                                                   \
    }

#define XWRITE(buf_)                                                            \
    {                                                                           \
        char* d_ = wv + (buf_) * WVBUF;                                         \
        _Pragma("unroll")                                                       \
        for (int k = 0; k < 5; ++k)                                             \
            if (cvalid[k]) {                                                    \
                u32 q_[4];                                                      \
                _Pragma("unroll")                                               \
                for (int jp = 0; jp < 4; ++jp) {                                \
                    float a0 = cok[k] ? v[k * 8 + 2 * jp] : 0.f;                \
                    float a1 = cok[k] ? v[k * 8 + 2 * jp + 1] : 0.f;            \
                    q_[jp] = (u32)bf16bits(a0) | ((u32)bf16bits(a1) << 16);     \
                }                                                               \
                *(int4*)(d_ + woff[k]) = *(int4*)q_;                            \
            }                                                                   \
    }

    // ---------- prologue: stage x(0), issue x(1) ----------
    XLOAD(0);
    XWRITE(0);
    XLOAD(1);
    LK0;

    // ---------- main loop: 8 cb x 5 taps, zero barriers ----------
#pragma unroll
    for (int cb = 0; cb < 8; ++cb) {
        const char* cur = wv + (cb & 1) * WVBUF;
#pragma unroll
        for (int t = 0; t < NK; ++t) {
            const int s = cb * NK + t;
            short8 af[4], bf[4];
            {
                const char* wtp = wimg + (size_t)s * WSTEP;
#pragma unroll
                for (int mi = 0; mi < 4; ++mi)
                    af[mi] = *(const short8*)(wtp + (afrow + mi * 16) * 64 + g * 16);
            }
#pragma unroll
            for (int ni = 0; ni < 4; ++ni) {
                int rx = ni * 16 + mrow + t;
                bf[ni] = *(const short8*)(cur + rx * 64 + ((g * 16) ^ XSWZ(rx)));
            }
            __builtin_amdgcn_s_setprio(1);
#pragma unroll
            for (int mi = 0; mi < 4; ++mi)
#pragma unroll
                for (int ni = 0; ni < 4; ++ni)
                    acc[mi][ni] = __builtin_amdgcn_mfma_f32_16x16x32_bf16(
                        af[mi], bf[ni], acc[mi][ni], 0, 0, 0);
            __builtin_amdgcn_s_setprio(0);
        }
        if (cb < 7) {
            XWRITE((cb + 1) & 1);      // waits v(cb+1) loads (one compute phase of cover)
            if (cb < 6) XLOAD(cb + 2); // issue next cluster
            LK0;                        // own ds_writes visible before own reads
        }
    }

    // ---------- epilogue: C/D col=lane&15 (w), row=g*4+r (co) ----------
#pragma unroll
    for (int mi = 0; mi < 4; ++mi) {
        int cobase = wave * 64 + mi * 16 + g * 4;
        float bv[4];
#pragma unroll
        for (int r = 0; r < 4; ++r) bv[r] = bias[cobase + r];
#pragma unroll
        for (int r = 0; r < 4; ++r) {
            float* orow = out + ((size_t)b * NCO + cobase + r) * NW + w0 + mrow;
#pragma unroll
            for (int ni = 0; ni < 4; ++ni)
                orow[ni * 16] = acc[mi][ni][r] + bv[r];
        }
    }
#undef XLOAD
#undef XWRITE
}

// ---------------- fallback (ws too small): naive fp32 ----------------

__global__ void conv_naive(const float* __restrict__ x, const float* __restrict__ wgt,
                           const float* __restrict__ bias, float* __restrict__ out) {
    int w  = blockIdx.x * 256 + threadIdx.x;
    int co = blockIdx.y;
    int b  = blockIdx.z;
    float acc = bias[co];
    for (int ci = 0; ci < NCI; ci++) {
        const float* xr = x + ((size_t)b * NCI + ci) * NW;
        const float* wr = wgt + ((size_t)co * NCI + ci) * NK;
#pragma unroll
        for (int k = 0; k < NK; k++) {
            int wi = w + k - 2;
            if (wi >= 0 && wi < NW) acc += xr[wi] * wr[k];
        }
    }
    out[((size_t)b * NCO + co) * NW + w] = acc;
}

// ---------------- launch ----------------

extern "C" void kernel_launch(void* const* d_in, const int* in_sizes, int n_in,
                              void* d_out, int out_size, void* d_ws, size_t ws_size,
                              hipStream_t stream) {
    const float* x    = (const float*)d_in[0];
    const float* wgt  = (const float*)d_in[1];
    const float* bias = (const float*)d_in[2];
    float* out        = (float*)d_out;

    if (ws_size < (size_t)W2_BYTES) {
        conv_naive<<<dim3(NW / 256, NCO, NB), 256, 0, stream>>>(x, wgt, bias, out);
        return;
    }

    u16* W2 = (u16*)d_ws;
    wprep<<<(NCO * NCI * NK + 255) / 256, 256, 0, stream>>>(wgt, W2);
    conv_mfma<<<2048, 256, 0, stream>>>(x, W2, bias, out);
}

// Round 17
// 141.604 us; speedup vs baseline: 2.0499x; 1.7265x over previous
//
#include <hip/hip_runtime.h>
#include <hip/hip_bf16.h>

typedef unsigned short u16;
typedef unsigned int u32;
typedef __attribute__((ext_vector_type(8))) short short8;
typedef __attribute__((ext_vector_type(4))) float floatx4;

#define NB 32
#define NCI 256
#define NCO 256
#define NW 4096
#define NK 5

#define WSTEP 16384                     // per (cb,t) W tile, pre-swizzled
#define W2_BYTES (40 * WSTEP)           // 655360
#define WREG 32768                      // granule W region (2 tiles max)

#define XROWB 64
#define XROWS 260                       // rloc = (w-w0)+2, 0..259
#define XBUF (XROWS * XROWB)            // 16640
#define XSWZ(r) ((((r) >> 1) & 3) << 4) // conflict-free r6-r16

#define FENCE asm volatile("" ::: "memory")
#define LK0   asm volatile("s_waitcnt lgkmcnt(0)" ::: "memory")
#define VM0   asm volatile("s_waitcnt vmcnt(0)" ::: "memory")

// ---------------- pre-kernel: W fp32 -> bf16, pre-swizzled DMA image ----------------

__global__ void wprep(const float* __restrict__ wgt, u16* __restrict__ W2) {
    int i = blockIdx.x * 256 + threadIdx.x;        // co*1280 + ci*5 + k
    if (i >= NCO * NCI * NK) return;
    int k  = i % NK;
    int ci = (i / NK) % NCI;
    int co = i / (NCI * NK);
    int cb = ci >> 5, cr = ci & 31;
    int s    = cb * NK + k;
    int slot = (cr >> 3) ^ ((co >> 1) & 3);        // T21 pre-swizzle
    __hip_bfloat16 h = __float2bfloat16(wgt[i]);
    W2[(size_t)(s * 256 + co) * 32 + slot * 8 + (cr & 7)] = *reinterpret_cast<u16*>(&h);
}

__device__ __forceinline__ u16 bf16bits(float f) {
    __hip_bfloat16 h = __float2bfloat16(f);
    return *reinterpret_cast<u16*>(&h);
}

__device__ __forceinline__ void gload_lds16(const void* gsrc, void* ldst) {
    __builtin_amdgcn_global_load_lds(
        (const __attribute__((address_space(1))) unsigned int*)gsrc,
        (__attribute__((address_space(3))) unsigned int*)ldst, 16, 0, 0);
}

// ---------------- fused conv: r9 schedule at GRANULE = tap-pair (24 steps, not 40) ----------------
// grid 512 = 16 wt x 32 b; block 512 = 8 waves; wave tile 128co x 64w; acc[8][4].
// Per cb: 3 granules {t0,t1}{t2,t3}{t4}. Granule: issue next-granule W-DMA
// (32/16KB -> rotating 2x32KB region), [j0: x issue-early], taps' frags+MFMA,
// [j2: x pack+write], vmcnt(0)+barrier. Full drains only (sound); 24 barriers.

__global__ __launch_bounds__(512, 2)
void conv_mfma(const float* __restrict__ x, const u16* __restrict__ W2,
               const float* __restrict__ bias, float* __restrict__ out) {
    __shared__ __align__(16) char smem[2 * WREG + 2 * XBUF];   // 98816 B
    char* const wlds = smem;
    char* const xlds = smem + 2 * WREG;

    const int bid  = blockIdx.x;
    const int wt   = bid & 15;
    const int b    = bid >> 4;
    const int tid  = threadIdx.x;
    const int lane = tid & 63;
    const int wave = tid >> 6;
    const int wm   = wave >> 2;
    const int wn   = wave & 3;
    const int mrow = lane & 15;
    const int g    = lane >> 4;
    const int w0   = wt * 256;

    floatx4 acc[8][4];
#pragma unroll
    for (int mi = 0; mi < 8; ++mi)
#pragma unroll
        for (int ni = 0; ni < 4; ++ni)
            acc[mi][ni] = (floatx4){0.f, 0.f, 0.f, 0.f};

    const float* xb   = x + (size_t)b * NCI * NW;
    const char*  wimg = (const char*)W2;

    // x staging: thread -> one w (wloc), 16 ci (half h); row rloc = 2 + wloc
    const int wloc = tid & 255;
    const int h    = tid >> 8;
    const int soff0 = (2 + wloc) * XROWB + ((h * 32) ^ XSWZ(2 + wloc));
    const int soff1 = (2 + wloc) * XROWB + ((h * 32 + 16) ^ XSWZ(2 + wloc));
    const float* xcol = xb + w0 + wloc;

    // halo: 1 uniform clamped load; lanes 0..15 of each wave write
    const int hidx = wave * 16 + (lane & 15);
    const int hri  = hidx >> 5;
    const int hci  = hidx & 31;
    const int hwg  = (hri < 2) ? (w0 - 2 + hri) : (w0 + 256 + (hri - 2));
    const int hwc  = (hwg < 0) ? 0 : ((hwg > NW - 1) ? (NW - 1) : hwg);
    const bool hok = (hwg >= 0) && (hwg < NW);
    const int hrloc = (hri < 2) ? hri : (258 + (hri - 2));
    const int hoff  = hrloc * XROWB + (((hci >> 3) ^ ((hrloc >> 1) & 3)) * 16) + (hci & 7) * 2;

    float v[16];
    float hvv = 0.f;

    // ---------- prologue: W granule-0 DMA (taps 0,1) + x(0) stage ----------
    {
#pragma unroll
        for (int k = 0; k < 4; ++k) {
            int c = wave + 8 * k;       // 32 chunks of 1 KB
            gload_lds16(wimg + c * 1024 + lane * 16, wlds + c * 1024);
        }
        float v0[16];
#pragma unroll
        for (int j = 0; j < 16; ++j)
            v0[j] = xcol[(size_t)(h * 16 + j) * NW];
        float hv0 = xb[(size_t)hci * NW + hwc];
        u32 p[8];
#pragma unroll
        for (int jp = 0; jp < 8; ++jp)
            p[jp] = (u32)bf16bits(v0[2 * jp]) | ((u32)bf16bits(v0[2 * jp + 1]) << 16);
        *(int4*)(xlds + soff0) = *(int4*)&p[0];
        *(int4*)(xlds + soff1) = *(int4*)&p[4];
        if ((lane & 63) < 16)
            *(u16*)(xlds + hoff) = bf16bits(hok ? hv0 : 0.f);
        LK0; VM0;
    }
    FENCE; __builtin_amdgcn_s_barrier(); FENCE;

    // ---------- main loop: 8 cb x 3 granules ----------
#pragma unroll
    for (int cb = 0; cb < 8; ++cb) {
        const char* xcur = xlds + (cb & 1) * XBUF;
        char* xnxt       = xlds + ((cb + 1) & 1) * XBUF;
#pragma unroll
        for (int j = 0; j < 3; ++j) {
            const int gr = cb * 3 + j;                         // granule id 0..23
            const int fs = cb * 5 + (j == 0 ? 0 : (j == 1 ? 2 : 4));
            const int nt = (j == 2) ? 1 : 2;

            // 1. issue W-DMA for granule gr+1 into the other region
            if (gr < 23) {
                const int cbn = (gr + 1) / 3, jn = (gr + 1) % 3;
                const int fsn = cbn * 5 + (jn == 0 ? 0 : (jn == 1 ? 2 : 4));
                const int ntn = (jn == 2) ? 1 : 2;
                const char* src = wimg + (size_t)fsn * WSTEP;
                char* dst = wlds + ((gr + 1) & 1) * WREG;
#pragma unroll
                for (int k = 0; k < 2 * ntn; ++k) {
                    int c = wave + 8 * k;
                    gload_lds16(src + c * 1024 + lane * 16, dst + c * 1024);
                }
            }
            FENCE;
            // 2. j0: x issue-early for cb+1 (consumed at j2 pack; ~4 taps cover)
            if (j == 0 && cb < 7) {
                const float* sx = xcol + (size_t)((cb + 1) * 32 + h * 16) * NW;
#pragma unroll
                for (int jj = 0; jj < 16; ++jj)
                    v[jj] = sx[(size_t)jj * NW];
                hvv = xb[(size_t)((cb + 1) * 32 + hci) * NW + hwc];
            }
            FENCE;
            // 3. taps of this granule
#pragma unroll
            for (int tt = 0; tt < nt; ++tt) {
                const int s = fs + tt;
                const int t = s - cb * 5;
                const char* wcur = wlds + (gr & 1) * WREG + tt * WSTEP;
                short8 af[8], bf[4];
#pragma unroll
                for (int mi = 0; mi < 8; ++mi) {
                    int rw = wm * 128 + mi * 16 + mrow;
                    af[mi] = *(const short8*)(wcur + rw * 64 + ((g * 16) ^ XSWZ(rw)));
                }
#pragma unroll
                for (int ni = 0; ni < 4; ++ni) {
                    int rx = wn * 64 + ni * 16 + mrow + t;
                    bf[ni] = *(const short8*)(xcur + rx * XROWB + ((g * 16) ^ XSWZ(rx)));
                }
                __builtin_amdgcn_s_setprio(1);
#pragma unroll
                for (int mi = 0; mi < 8; ++mi)
#pragma unroll
                    for (int ni = 0; ni < 4; ++ni)
                        acc[mi][ni] = __builtin_amdgcn_mfma_f32_16x16x32_bf16(
                            af[mi], bf[ni], acc[mi][ni], 0, 0, 0);
                __builtin_amdgcn_s_setprio(0);
            }
            // 4. j2: pack + write-late x(cb+1)
            if (j == 2 && cb < 7) {
                u32 p[8];
#pragma unroll
                for (int jp = 0; jp < 8; ++jp)
                    p[jp] = (u32)bf16bits(v[2 * jp]) | ((u32)bf16bits(v[2 * jp + 1]) << 16);
                *(int4*)(xnxt + soff0) = *(int4*)&p[0];
                *(int4*)(xnxt + soff1) = *(int4*)&p[4];
                if ((lane & 63) < 16)
                    *(u16*)(xnxt + hoff) = bf16bits(hok ? hvv : 0.f);
            }
            // 5. granule end: full drain + barrier (skip after the last granule)
            if (gr < 23) {
                LK0; VM0;
                FENCE; __builtin_amdgcn_s_barrier(); FENCE;
            }
        }
    }

    // ---------- epilogue: C/D col=lane&15 (w), row=g*4+r (co) ----------
#pragma unroll
    for (int mi = 0; mi < 8; ++mi) {
        int cobase = wm * 128 + mi * 16 + g * 4;
        float bv[4];
#pragma unroll
        for (int r = 0; r < 4; ++r) bv[r] = bias[cobase + r];
#pragma unroll
        for (int ni = 0; ni < 4; ++ni) {
            int col = w0 + wn * 64 + ni * 16 + mrow;
#pragma unroll
            for (int r = 0; r < 4; ++r)
                out[((size_t)b * NCO + cobase + r) * NW + col] =
                    acc[mi][ni][r] + bv[r];
        }
    }
}

// ---------------- fallback (ws too small): naive fp32 ----------------

__global__ void conv_naive(const float* __restrict__ x, const float* __restrict__ wgt,
                           const float* __restrict__ bias, float* __restrict__ out) {
    int w  = blockIdx.x * 256 + threadIdx.x;
    int co = blockIdx.y;
    int b  = blockIdx.z;
    float acc = bias[co];
    for (int ci = 0; ci < NCI; ci++) {
        const float* xr = x + ((size_t)b * NCI + ci) * NW;
        const float* wr = wgt + ((size_t)co * NCI + ci) * NK;
#pragma unroll
        for (int k = 0; k < NK; k++) {
            int wi = w + k - 2;
            if (wi >= 0 && wi < NW) acc += xr[wi] * wr[k];
        }
    }
    out[((size_t)b * NCO + co) * NW + w] = acc;
}

// ---------------- launch ----------------

extern "C" void kernel_launch(void* const* d_in, const int* in_sizes, int n_in,
                              void* d_out, int out_size, void* d_ws, size_t ws_size,
                              hipStream_t stream) {
    const float* x    = (const float*)d_in[0];
    const float* wgt  = (const float*)d_in[1];
    const float* bias = (const float*)d_in[2];
    float* out        = (float*)d_out;

    if (ws_size < (size_t)W2_BYTES) {
        conv_naive<<<dim3(NW / 256, NCO, NB), 256, 0, stream>>>(x, wgt, bias, out);
        return;
    }

    u16* W2 = (u16*)d_ws;
    wprep<<<(NCO * NCI * NK + 255) / 256, 256, 0, stream>>>(wgt, W2);
    conv_mfma<<<512, 512, 0, stream>>>(x, W2, bias, out);
}